// Round 14
// baseline (605.273 us; speedup 1.0000x reference)
//
#include <hip/hip_runtime.h>

// DigitCaps routing via MFMA, u_hat never materialized. 8 dispatches.
// r14: squash fused into sgemm via last-arriver reduction (device-scope
// atomic counters, fixed-order sums -> deterministic, no spinning).
// B=512, R=1152, J=10, O=16, I=8, JO=160, K=R*I=9216.
// s[b,jo]    = sum_k x[b,k] * Wc[k,jo],  Wc[(r,i),(j,o)] = W[r,j,o,i]*c[r,j]
// v          = s*|s|/(1+s^2)
// biasT[j,r]+= (1/B) sum_{i,o} W[r,j,o,i] * M[(r,i),(j,o)],  M = x_r^T @ v
// c          = softmax_r(biasT)  (fused into wcstat, coalesced [j][r] reads)

#define B_   512
#define R_   1152
#define JO_  160
#define K_   9216
#define KS_  32
#define SPK_ 9

typedef __attribute__((ext_vector_type(4))) float f32x4;
typedef __attribute__((ext_vector_type(8))) short bf16x8;

__device__ __forceinline__ short f2bf(float f) {
  unsigned int u = __float_as_uint(f);
  unsigned int r = (u + 0x7FFFu + ((u >> 16) & 1u)) >> 16;
  return (short)r;
}

// ---- prep: biasT=0, cnt=0, xaf (s-GEMM A-frags), xtf (agree A-frags),
// wcf it0. grid 2304 x 256.
__global__ __launch_bounds__(256) void prep_kernel(
    const float* __restrict__ x, const float* __restrict__ W,
    short* __restrict__ xaf, short* __restrict__ xtf,
    short* __restrict__ wcf, float* __restrict__ biasT,
    unsigned* __restrict__ cnt) {
  int gid = blockIdx.x * 256 + threadIdx.x;  // < 589824
  if (gid < R_ * 10) biasT[gid] = 0.0f;
  if (gid < 480) cnt[gid] = 0u;  // 3 iters x 16 kb x 10 nb
  {  // xaf: frag f = m16*288+ks; lane l: row m16*16+(l&15), k=ks*32+(l>>4)*8+t
    int l = gid & 63, f = gid >> 6;
    int ks = f % 288, m16 = f / 288;
    int row = m16 * 16 + (l & 15);
    int k0 = ks * 32 + (l >> 4) * 8;
    const float4* p = (const float4*)(x + (size_t)row * K_ + k0);
    float4 a = p[0], b = p[1];
    bf16x8 pk;
    pk[0] = f2bf(a.x); pk[1] = f2bf(a.y); pk[2] = f2bf(a.z); pk[3] = f2bf(a.w);
    pk[4] = f2bf(b.x); pk[5] = f2bf(b.y); pk[6] = f2bf(b.z); pk[7] = f2bf(b.w);
    ((bf16x8*)xaf)[gid] = pk;
  }
  {  // xtf: frag f = rp*16+kb; lane l: row (l&15) of r-pair rp, k=b
    int l = gid & 63, f = gid >> 6;
    int kb = f & 15, rp = f >> 4;
    int b0 = kb * 32 + (l >> 4) * 8;
    const float* p = x + (size_t)b0 * K_ + rp * 16 + (l & 15);
    bf16x8 pk;
#pragma unroll
    for (int t = 0; t < 8; ++t) pk[t] = f2bf(p[(size_t)t * K_]);
    ((bf16x8*)xtf)[gid] = pk;
  }
  if (gid < 184320) {  // wcf iter0: unscaled W (c=1/R folded in sgemm epilogue)
    int l = gid & 63;
    int rest = gid >> 6;
    int nb = rest % 10, kb = rest / 10;
    int r = kb * 4 + (l >> 4);
    int o = l & 15;
    const float4* wp = (const float4*)(W + (((size_t)r * 10 + nb) * 16 + o) * 8);
    float4 a = wp[0], b = wp[1];
    bf16x8 pk;
    pk[0] = f2bf(a.x); pk[1] = f2bf(a.y); pk[2] = f2bf(a.z); pk[3] = f2bf(a.w);
    pk[4] = f2bf(b.x); pk[5] = f2bf(b.y); pk[6] = f2bf(b.z); pk[7] = f2bf(b.w);
    ((bf16x8*)wcf)[gid] = pk;
  }
}

// ---- wcstat: softmax stats (coalesced biasT[j][r] reads, redundant per
// block, fixed order) + Wc build. grid 720 x 256.
__global__ __launch_bounds__(256) void wcstat_kernel(
    const float* __restrict__ W, const float* __restrict__ biasT,
    short* __restrict__ wcf) {
  __shared__ float mzs[20];
  const int tid = threadIdx.x;
  const int w = tid >> 6, lane = tid & 63;
  for (int j = w; j < 10; j += 4) {
    float pv[18];
#pragma unroll
    for (int t = 0; t < 18; ++t) pv[t] = biasT[j * R_ + t * 64 + lane];
    float m = -1e30f;
#pragma unroll
    for (int t = 0; t < 18; ++t) m = fmaxf(m, pv[t]);
#pragma unroll
    for (int d = 32; d; d >>= 1) m = fmaxf(m, __shfl_xor(m, d));
    float s = 0.0f;
#pragma unroll
    for (int t = 0; t < 18; ++t) s += expf(pv[t] - m);
#pragma unroll
    for (int d = 32; d; d >>= 1) s += __shfl_xor(s, d);
    if (lane == 0) {
      mzs[j] = m;
      mzs[10 + j] = 1.0f / s;
    }
  }
  __syncthreads();
  int idx = blockIdx.x * 256 + tid;  // < 184320
  int l = idx & 63;
  int rest = idx >> 6;
  int nb = rest % 10, kb = rest / 10;
  int r = kb * 4 + (l >> 4);
  int o = l & 15;
  const float4* wp = (const float4*)(W + (((size_t)r * 10 + nb) * 16 + o) * 8);
  float4 a = wp[0], b = wp[1];
  float cs = expf(biasT[nb * R_ + r] - mzs[nb]) * mzs[10 + nb];
  bf16x8 pk;
  pk[0] = f2bf(a.x * cs); pk[1] = f2bf(a.y * cs);
  pk[2] = f2bf(a.z * cs); pk[3] = f2bf(a.w * cs);
  pk[4] = f2bf(b.x * cs); pk[5] = f2bf(b.y * cs);
  pk[6] = f2bf(b.z * cs); pk[7] = f2bf(b.w * cs);
  ((bf16x8*)wcf)[idx] = pk;
}

// ---- s-GEMM + fused last-arriver squash.
// grid (8, 32); 4 waves share one 9-step wcf k-slice (L1 reuse), wave = one
// m16-tile x 160. Tiled part writes part[ks][nb][kb][32][16]. For a given
// (kb,nb) exactly the 32 ks-blocks of m-group kb/2 contribute; the 32nd
// arriver (atomicAdd ret 31) reduces in fixed ks order + squashes + emits.
template <bool SCALE>
__global__ __launch_bounds__(256) void sgemm_kernel(
    const short* __restrict__ xaf, const short* __restrict__ wcf,
    float* __restrict__ part, unsigned* __restrict__ cnt,
    short* __restrict__ vfrag, float* __restrict__ out) {
  __shared__ unsigned flags;
  __shared__ float vtile[32][17];
  const int tid = threadIdx.x;
  const int w = tid >> 6, lane = tid & 63;
  const int m16 = blockIdx.x * 4 + w;
  const int ks0 = blockIdx.y * SPK_;

  f32x4 acc[10] = {};
  const bf16x8* ap = (const bf16x8*)xaf + ((size_t)m16 * 288 + ks0) * 64 + lane;
  const bf16x8* bp = (const bf16x8*)wcf + ((size_t)ks0 * 640 + lane);
  for (int st = 0; st < SPK_; ++st) {
    bf16x8 af = ap[0];
    ap += 64;
#pragma unroll
    for (int nb = 0; nb < 10; ++nb)
      acc[nb] = __builtin_amdgcn_mfma_f32_16x16x32_bf16(af, bp[nb * 64],
                                                        acc[nb], 0, 0, 0);
    bp += 640;
  }
  // C/D: col=lane&15, row=(lane>>4)*4+q; dest part[ks][nb][kb][32][16]
  {
    const float scale = SCALE ? (1.0f / 1152.0f) : 1.0f;
    const int kb = m16 >> 1;
    const int bl0 = (m16 & 1) * 16 + (lane >> 4) * 4;
    const int colc = lane & 15;
#pragma unroll
    for (int nb = 0; nb < 10; ++nb)
#pragma unroll
      for (int q = 0; q < 4; ++q)
        part[((((size_t)blockIdx.y * 10 + nb) * 16 + kb) * 32 + bl0 + q) * 16 +
             colc] = acc[nb][q] * scale;
  }
  // ---- last-arriver detection (no spinning; deterministic fixed-order sums)
  __threadfence();  // release this block's part writes (device scope)
  if (tid == 0) flags = 0u;
  __syncthreads();
  if (tid < 20) {
    int kb = (blockIdx.x << 1) + (tid >= 10);
    int nb = (tid >= 10) ? tid - 10 : tid;
    unsigned ret = atomicAdd(&cnt[kb * 10 + nb], 1u);
    if (ret == 31u) atomicOr(&flags, 1u << tid);
  }
  __syncthreads();
  unsigned fl = flags;
  if (fl == 0u) return;
  __threadfence();  // acquire all 32 writers' part planes
  while (fl) {
    int f = __ffs(fl) - 1;
    fl &= fl - 1u;
    const int kb = (blockIdx.x << 1) + (f >= 10);
    const int nb = (f >= 10) ? f - 10 : f;
    const int bl = tid >> 2, c4 = (tid & 3) * 4;
    float4 v4;
    if (tid < 128) {
      const float4* pe = (const float4*)(
          part + (((size_t)nb * 16 + kb) * 32 + bl) * 16 + c4);
      float4 s4 = {0.0f, 0.0f, 0.0f, 0.0f};
#pragma unroll
      for (int ks = 0; ks < KS_; ++ks) {
        float4 p = pe[(size_t)ks * (B_ * JO_ / 4)];
        s4.x += p.x; s4.y += p.y; s4.z += p.z; s4.w += p.w;
      }
      v4.x = s4.x * fabsf(s4.x) / (1.0f + s4.x * s4.x);
      v4.y = s4.y * fabsf(s4.y) / (1.0f + s4.y * s4.y);
      v4.z = s4.z * fabsf(s4.z) / (1.0f + s4.z * s4.z);
      v4.w = s4.w * fabsf(s4.w) / (1.0f + s4.w * s4.w);
      if (out)
        *(float4*)(out + (size_t)(kb * 32 + bl) * JO_ + nb * 16 + c4) = v4;
    }
    if (vfrag) {
      __syncthreads();  // protect vtile across f-iterations
      if (tid < 128) {
        vtile[bl][c4] = v4.x;
        vtile[bl][c4 + 1] = v4.y;
        vtile[bl][c4 + 2] = v4.z;
        vtile[bl][c4 + 3] = v4.w;
      }
      __syncthreads();
      if (tid < 64) {
        bf16x8 pk;
#pragma unroll
        for (int t = 0; t < 8; ++t)
          pk[t] = f2bf(vtile[(tid >> 4) * 8 + t][tid & 15]);
        ((bf16x8*)vfrag)[((size_t)kb * 10 + nb) * 64 + tid] = pk;
      }
    }
  }
}

// ---- agree: per r-pair M[16x160] = x_r^T @ v (K=B=512, 4 waves x 128),
// then biasT[j][r] += (1/B) sum_{i,o} W*M, fused. grid 576 x 256.
__global__ __launch_bounds__(256) void agree_kernel(
    const short* __restrict__ xtf, const float* __restrict__ W,
    const short* __restrict__ vfrag, float* __restrict__ biasT) {
  __shared__ float Msm[4][16][176];
  __shared__ float red[320];
  const int tid = threadIdx.x;
  const int w = tid >> 6, lane = tid & 63;
  const int rp = blockIdx.x;
  const int r0 = rp * 2;

  f32x4 acc[10] = {};
  const bf16x8* ap = (const bf16x8*)xtf + ((size_t)rp * 16 + w * 4) * 64 + lane;
  const bf16x8* bp = (const bf16x8*)vfrag + ((size_t)(w * 4) * 640 + lane);
#pragma unroll
  for (int ks = 0; ks < 4; ++ks) {
    bf16x8 af = ap[0];
    ap += 64;
#pragma unroll
    for (int nb = 0; nb < 10; ++nb)
      acc[nb] = __builtin_amdgcn_mfma_f32_16x16x32_bf16(af, bp[nb * 64],
                                                        acc[nb], 0, 0, 0);
    bp += 640;
  }
  {
    int colc = lane & 15, rbase = (lane >> 4) * 4;
#pragma unroll
    for (int nb = 0; nb < 10; ++nb)
#pragma unroll
      for (int q = 0; q < 4; ++q)
        Msm[w][rbase + q][nb * 16 + colc] = acc[nb][q];
  }
  __syncthreads();
  for (int idx = tid; idx < 320; idx += 256) {
    int rr = idx / 160, jo = idx - rr * 160;
    int j = jo >> 4, o = jo & 15;
    float p = 0.0f;
    const float* wp = W + (((size_t)(r0 + rr) * 10 + j) * 16 + o) * 8;
#pragma unroll
    for (int i = 0; i < 8; ++i) {
      float m = Msm[0][rr * 8 + i][jo] + Msm[1][rr * 8 + i][jo] +
                Msm[2][rr * 8 + i][jo] + Msm[3][rr * 8 + i][jo];
      p += wp[i] * m;
    }
    red[idx] = p;
  }
  __syncthreads();
  if (tid < 20) {
    int rr = tid / 10, j = tid - rr * 10;
    float s = 0.0f;
#pragma unroll
    for (int o = 0; o < 16; ++o) s += red[rr * 160 + j * 16 + o];
    biasT[j * R_ + (r0 + rr)] += s * (1.0f / 512.0f);
  }
}

extern "C" void kernel_launch(void* const* d_in, const int* in_sizes, int n_in,
                              void* d_out, int out_size, void* d_ws,
                              size_t ws_size, hipStream_t stream) {
  const float* x = (const float*)d_in[0];  // [512,1152,8]
  const float* W = (const float*)d_in[1];  // [1152,10,16,8]
  float* out = (float*)d_out;              // [512][160]
  char* ws = (char*)d_ws;

  // layout (bytes):
  float*    biasT = (float*)(ws);             // 46080
  unsigned* cnt   = (unsigned*)(ws + 46080);  // 1920 (3x16x10)
  short*    vfrag = (short*)(ws + 48128);     // 163840
  short*    wcf   = (short*)(ws + 211968);    // 2949120
  short*    xaf   = (short*)(ws + 3161088);   // 9437184
  short*    xtf   = (short*)(ws + 12598272);  // 9437184
  float*    part  = (float*)(ws + 22035456);  // 32*327680 = 10485760

  prep_kernel<<<2304, 256, 0, stream>>>(x, W, xaf, xtf, wcf, biasT, cnt);

  // iter 0 (c uniform, folded as 1/1152 epilogue scale; wcf from prep)
  sgemm_kernel<true><<<dim3(8, KS_), 256, 0, stream>>>(xaf, wcf, part,
                                                       cnt, vfrag, nullptr);
  agree_kernel<<<576, 256, 0, stream>>>(xtf, W, vfrag, biasT);
  wcstat_kernel<<<720, 256, 0, stream>>>(W, biasT, wcf);
  // iter 1
  sgemm_kernel<false><<<dim3(8, KS_), 256, 0, stream>>>(xaf, wcf, part,
                                                        cnt + 160, vfrag,
                                                        nullptr);
  agree_kernel<<<576, 256, 0, stream>>>(xtf, W, vfrag, biasT);
  wcstat_kernel<<<720, 256, 0, stream>>>(W, biasT, wcf);
  // iter 2
  sgemm_kernel<false><<<dim3(8, KS_), 256, 0, stream>>>(xaf, wcf, part,
                                                        cnt + 320, nullptr,
                                                        out);
}

// Round 15
// 86.567 us; speedup vs baseline: 6.9919x; 6.9919x over previous
//
#include <hip/hip_runtime.h>

// DigitCaps routing via MFMA, u_hat never materialized. Multi-kernel,
// 11 dispatches — the measured champion structure (r11, 87.0us).
// Reverted from r14: a device-scope __threadfence() per sgemm block forced
// non-coherent per-XCD L2 writebacks -> 181us/call. Dispatch boundaries
// (~1-2us) remain the only cheap cross-XCD ordering primitive on gfx950.
// B=512, R=1152, J=10, O=16, I=8, JO=160, K=R*I=9216.
// s[b,jo]    = sum_k x[b,k] * Wc[k,jo],  Wc[(r,i),(j,o)] = W[r,j,o,i]*c[r,j]
// v          = s*|s|/(1+s^2)
// biasT[j,r]+= (1/B) sum_{i,o} W[r,j,o,i] * M[(r,i),(j,o)],  M = x_r^T @ v
// c          = softmax_r(biasT)  (fused into wcstat, coalesced [j][r] reads)
//
// sgemm: 4 waves/block share one wcf k-slice (L1 reuse x4) and write part in
// tiled [ks][nb][kb][32][16] layout so squash reads are contiguous.
// All reductions fixed-order -> deterministic.

#define B_   512
#define R_   1152
#define JO_  160
#define K_   9216
#define KS_  32
#define SPK_ 9

typedef __attribute__((ext_vector_type(4))) float f32x4;
typedef __attribute__((ext_vector_type(8))) short bf16x8;

__device__ __forceinline__ short f2bf(float f) {
  unsigned int u = __float_as_uint(f);
  unsigned int r = (u + 0x7FFFu + ((u >> 16) & 1u)) >> 16;
  return (short)r;
}

// ---- prep: biasT=0, xaf (s-GEMM A-frags), xtf (agree A-frags), wcf it0.
// grid 2304 x 256.
__global__ __launch_bounds__(256) void prep_kernel(
    const float* __restrict__ x, const float* __restrict__ W,
    short* __restrict__ xaf, short* __restrict__ xtf,
    short* __restrict__ wcf, float* __restrict__ biasT) {
  int gid = blockIdx.x * 256 + threadIdx.x;  // < 589824
  if (gid < R_ * 10) biasT[gid] = 0.0f;
  {  // xaf: frag f = m16*288+ks; lane l: row m16*16+(l&15), k=ks*32+(l>>4)*8+t
    int l = gid & 63, f = gid >> 6;
    int ks = f % 288, m16 = f / 288;
    int row = m16 * 16 + (l & 15);
    int k0 = ks * 32 + (l >> 4) * 8;
    const float4* p = (const float4*)(x + (size_t)row * K_ + k0);
    float4 a = p[0], b = p[1];
    bf16x8 pk;
    pk[0] = f2bf(a.x); pk[1] = f2bf(a.y); pk[2] = f2bf(a.z); pk[3] = f2bf(a.w);
    pk[4] = f2bf(b.x); pk[5] = f2bf(b.y); pk[6] = f2bf(b.z); pk[7] = f2bf(b.w);
    ((bf16x8*)xaf)[gid] = pk;
  }
  {  // xtf: frag f = rp*16+kb; lane l: row (l&15) of r-pair rp, k=b
    int l = gid & 63, f = gid >> 6;
    int kb = f & 15, rp = f >> 4;
    int b0 = kb * 32 + (l >> 4) * 8;
    const float* p = x + (size_t)b0 * K_ + rp * 16 + (l & 15);
    bf16x8 pk;
#pragma unroll
    for (int t = 0; t < 8; ++t) pk[t] = f2bf(p[(size_t)t * K_]);
    ((bf16x8*)xtf)[gid] = pk;
  }
  if (gid < 184320) {  // wcf iter0: unscaled W (c=1/R folded in sgemm epilogue)
    int l = gid & 63;
    int rest = gid >> 6;
    int nb = rest % 10, kb = rest / 10;
    int r = kb * 4 + (l >> 4);
    int o = l & 15;
    const float4* wp = (const float4*)(W + (((size_t)r * 10 + nb) * 16 + o) * 8);
    float4 a = wp[0], b = wp[1];
    bf16x8 pk;
    pk[0] = f2bf(a.x); pk[1] = f2bf(a.y); pk[2] = f2bf(a.z); pk[3] = f2bf(a.w);
    pk[4] = f2bf(b.x); pk[5] = f2bf(b.y); pk[6] = f2bf(b.z); pk[7] = f2bf(b.w);
    ((bf16x8*)wcf)[gid] = pk;
  }
}

// ---- wcstat: softmax stats (coalesced biasT[j][r] reads, redundant per
// block, fixed order) + Wc build. grid 720 x 256.
__global__ __launch_bounds__(256) void wcstat_kernel(
    const float* __restrict__ W, const float* __restrict__ biasT,
    short* __restrict__ wcf) {
  __shared__ float mzs[20];
  const int tid = threadIdx.x;
  const int w = tid >> 6, lane = tid & 63;
  for (int j = w; j < 10; j += 4) {
    float pv[18];
#pragma unroll
    for (int t = 0; t < 18; ++t) pv[t] = biasT[j * R_ + t * 64 + lane];
    float m = -1e30f;
#pragma unroll
    for (int t = 0; t < 18; ++t) m = fmaxf(m, pv[t]);
#pragma unroll
    for (int d = 32; d; d >>= 1) m = fmaxf(m, __shfl_xor(m, d));
    float s = 0.0f;
#pragma unroll
    for (int t = 0; t < 18; ++t) s += expf(pv[t] - m);
#pragma unroll
    for (int d = 32; d; d >>= 1) s += __shfl_xor(s, d);
    if (lane == 0) {
      mzs[j] = m;
      mzs[10 + j] = 1.0f / s;
    }
  }
  __syncthreads();
  int idx = blockIdx.x * 256 + tid;  // < 184320
  int l = idx & 63;
  int rest = idx >> 6;
  int nb = rest % 10, kb = rest / 10;
  int r = kb * 4 + (l >> 4);
  int o = l & 15;
  const float4* wp = (const float4*)(W + (((size_t)r * 10 + nb) * 16 + o) * 8);
  float4 a = wp[0], b = wp[1];
  float cs = expf(biasT[nb * R_ + r] - mzs[nb]) * mzs[10 + nb];
  bf16x8 pk;
  pk[0] = f2bf(a.x * cs); pk[1] = f2bf(a.y * cs);
  pk[2] = f2bf(a.z * cs); pk[3] = f2bf(a.w * cs);
  pk[4] = f2bf(b.x * cs); pk[5] = f2bf(b.y * cs);
  pk[6] = f2bf(b.z * cs); pk[7] = f2bf(b.w * cs);
  ((bf16x8*)wcf)[idx] = pk;
}

// ---- s-GEMM: grid (8, 32); 4 waves share one 9-step wcf k-slice (L1 reuse),
// wave = one m16-tile x 160. Tiled part writes part[ks][nb][kb][32][16].
template <bool SCALE>
__global__ __launch_bounds__(256) void sgemm_kernel(
    const short* __restrict__ xaf, const short* __restrict__ wcf,
    float* __restrict__ part) {
  const int tid = threadIdx.x;
  const int w = tid >> 6, lane = tid & 63;
  const int m16 = blockIdx.x * 4 + w;
  const int ks0 = blockIdx.y * SPK_;

  f32x4 acc[10] = {};
  const bf16x8* ap = (const bf16x8*)xaf + ((size_t)m16 * 288 + ks0) * 64 + lane;
  const bf16x8* bp = (const bf16x8*)wcf + ((size_t)ks0 * 640 + lane);
  for (int st = 0; st < SPK_; ++st) {
    bf16x8 af = ap[0];
    ap += 64;
#pragma unroll
    for (int nb = 0; nb < 10; ++nb)
      acc[nb] = __builtin_amdgcn_mfma_f32_16x16x32_bf16(af, bp[nb * 64],
                                                        acc[nb], 0, 0, 0);
    bp += 640;
  }
  // C/D: col=lane&15, row=(lane>>4)*4+q; dest part[ks][nb][kb][32][16]
  const float scale = SCALE ? (1.0f / 1152.0f) : 1.0f;
  const int kb = m16 >> 1;
  const int bl0 = (m16 & 1) * 16 + (lane >> 4) * 4;
  const int colc = lane & 15;
#pragma unroll
  for (int nb = 0; nb < 10; ++nb)
#pragma unroll
    for (int q = 0; q < 4; ++q)
      part[((((size_t)blockIdx.y * 10 + nb) * 16 + kb) * 32 + bl0 + q) * 16 +
           colc] = acc[nb][q] * scale;
}

// ---- squash: reduce 32 tiled planes + squash; grid 160 (one (kb,nb) tile),
// block 512, 1 element/thread; per-plane reads are contiguous 2KB runs.
__global__ __launch_bounds__(512) void squash_kernel(
    const float* __restrict__ part, short* __restrict__ vfrag,
    float* __restrict__ out) {
  __shared__ float vsm[32][17];
  const int tid = threadIdx.x;  // 0..511
  const int kb = blockIdx.x / 10, nb = blockIdx.x - (blockIdx.x / 10) * 10;
  const int bl = tid >> 4, col = tid & 15;
  const float* pe = part + (((size_t)nb * 16 + kb) * 32 + bl) * 16 + col;
  float pv[KS_];
#pragma unroll
  for (int ks = 0; ks < KS_; ++ks) pv[ks] = pe[(size_t)ks * (B_ * JO_)];
  float s = 0.0f;
#pragma unroll
  for (int ks = 0; ks < KS_; ++ks) s += pv[ks];
  float val = s * fabsf(s) / (1.0f + s * s);
  if (out) out[(size_t)(kb * 32 + bl) * JO_ + nb * 16 + col] = val;
  if (vfrag) {
    vsm[bl][col] = val;
    __syncthreads();
    if (tid < 64) {
      bf16x8 pk;
#pragma unroll
      for (int t = 0; t < 8; ++t)
        pk[t] = f2bf(vsm[(tid >> 4) * 8 + t][tid & 15]);
      ((bf16x8*)vfrag)[(size_t)blockIdx.x * 64 + tid] = pk;
    }
  }
}

// ---- agree: per r-pair M[16x160] = x_r^T @ v (K=B=512, 4 waves x 128),
// then biasT[j][r] += (1/B) sum_{i,o} W*M, fused. grid 576 x 256.
__global__ __launch_bounds__(256) void agree_kernel(
    const short* __restrict__ xtf, const float* __restrict__ W,
    const short* __restrict__ vfrag, float* __restrict__ biasT) {
  __shared__ float Msm[4][16][176];
  __shared__ float red[320];
  const int tid = threadIdx.x;
  const int w = tid >> 6, lane = tid & 63;
  const int rp = blockIdx.x;
  const int r0 = rp * 2;

  f32x4 acc[10] = {};
  const bf16x8* ap = (const bf16x8*)xtf + ((size_t)rp * 16 + w * 4) * 64 + lane;
  const bf16x8* bp = (const bf16x8*)vfrag + ((size_t)(w * 4) * 640 + lane);
#pragma unroll
  for (int ks = 0; ks < 4; ++ks) {
    bf16x8 af = ap[0];
    ap += 64;
#pragma unroll
    for (int nb = 0; nb < 10; ++nb)
      acc[nb] = __builtin_amdgcn_mfma_f32_16x16x32_bf16(af, bp[nb * 64],
                                                        acc[nb], 0, 0, 0);
    bp += 640;
  }
  {
    int colc = lane & 15, rbase = (lane >> 4) * 4;
#pragma unroll
    for (int nb = 0; nb < 10; ++nb)
#pragma unroll
      for (int q = 0; q < 4; ++q)
        Msm[w][rbase + q][nb * 16 + colc] = acc[nb][q];
  }
  __syncthreads();
  for (int idx = tid; idx < 320; idx += 256) {
    int rr = idx / 160, jo = idx - rr * 160;
    int j = jo >> 4, o = jo & 15;
    float p = 0.0f;
    const float* wp = W + (((size_t)(r0 + rr) * 10 + j) * 16 + o) * 8;
#pragma unroll
    for (int i = 0; i < 8; ++i) {
      float m = Msm[0][rr * 8 + i][jo] + Msm[1][rr * 8 + i][jo] +
                Msm[2][rr * 8 + i][jo] + Msm[3][rr * 8 + i][jo];
      p += wp[i] * m;
    }
    red[idx] = p;
  }
  __syncthreads();
  if (tid < 20) {
    int rr = tid / 10, j = tid - rr * 10;
    float s = 0.0f;
#pragma unroll
    for (int o = 0; o < 16; ++o) s += red[rr * 160 + j * 16 + o];
    biasT[j * R_ + (r0 + rr)] += s * (1.0f / 512.0f);
  }
}

extern "C" void kernel_launch(void* const* d_in, const int* in_sizes, int n_in,
                              void* d_out, int out_size, void* d_ws,
                              size_t ws_size, hipStream_t stream) {
  const float* x = (const float*)d_in[0];  // [512,1152,8]
  const float* W = (const float*)d_in[1];  // [1152,10,16,8]
  float* out = (float*)d_out;              // [512][160]
  char* ws = (char*)d_ws;

  // layout (bytes):
  float* biasT = (float*)(ws);             // 46080
  short* vfrag = (short*)(ws + 46080);     // 163840
  short* wcf   = (short*)(ws + 209920);    // 2949120
  short* xaf   = (short*)(ws + 3159040);   // 9437184
  short* xtf   = (short*)(ws + 12596224);  // 9437184
  float* part  = (float*)(ws + 22033408);  // 32*327680 = 10485760

  prep_kernel<<<2304, 256, 0, stream>>>(x, W, xaf, xtf, wcf, biasT);

  // iter 0 (c uniform, folded as 1/1152 epilogue scale; wcf from prep)
  sgemm_kernel<true><<<dim3(8, KS_), 256, 0, stream>>>(xaf, wcf, part);
  squash_kernel<<<160, 512, 0, stream>>>(part, vfrag, nullptr);
  agree_kernel<<<576, 256, 0, stream>>>(xtf, W, vfrag, biasT);
  wcstat_kernel<<<720, 256, 0, stream>>>(W, biasT, wcf);
  // iter 1
  sgemm_kernel<false><<<dim3(8, KS_), 256, 0, stream>>>(xaf, wcf, part);
  squash_kernel<<<160, 512, 0, stream>>>(part, vfrag, nullptr);
  agree_kernel<<<576, 256, 0, stream>>>(xtf, W, vfrag, biasT);
  wcstat_kernel<<<720, 256, 0, stream>>>(W, biasT, wcf);
  // iter 2
  sgemm_kernel<false><<<dim3(8, KS_), 256, 0, stream>>>(xaf, wcf, part);
  squash_kernel<<<160, 512, 0, stream>>>(part, nullptr, out);
}